// Round 1
// baseline (602.705 us; speedup 1.0000x reference)
//
#include <hip/hip_runtime.h>

#define T_LEN 4096
#define NB    32
#define CIN   64
#define CH    32
#define COUT  448
#define TT_OUT 253   // 256 threads - 3 halo columns
#define BLK_A 256
#define TR_B  128

// gated activation: tanh(d) * sigmoid(d)
__device__ __forceinline__ float gated(float d) {
  float dc = fminf(fmaxf(d, -30.0f), 30.0f);   // guard exp overflow; saturated region anyway
  float e2 = __expf(-2.0f * dc);
  float th = (1.0f - e2) / (1.0f + e2);
  float sg = 1.0f / (1.0f + __expf(-dc));
  return th * sg;
}

// Fused front end: causal conv -> 2 gated residual blocks -> skip head -> h [B*T, 32]
// One thread per timestep; t = blockIdx.x*TT_OUT - 3 + tid (3-column halo).
// LDS layout [ch][col]: lane-consecutive columns -> stride-1 -> conflict-free.
__global__ __launch_bounds__(BLK_A) void dicnn_front(
    const float* __restrict__ x,
    const float* __restrict__ w_causal, const float* __restrict__ b_causal,
    const float* __restrict__ wd0, const float* __restrict__ bd0,
    const float* __restrict__ ws0, const float* __restrict__ bs0,
    const float* __restrict__ wo0, const float* __restrict__ bo0,
    const float* __restrict__ wd1, const float* __restrict__ bd1,
    const float* __restrict__ ws1, const float* __restrict__ bs1,
    const float* __restrict__ w_sk1, const float* __restrict__ b_sk1,
    float* __restrict__ h_out)
{
  __shared__ float zbuf[CH][BLK_A];
  __shared__ float gbuf[CH][BLK_A];

  const int tid = threadIdx.x;
  const int b   = blockIdx.y;
  const int t   = blockIdx.x * TT_OUT - 3 + tid;

  // ---- phase 1: z0 = causal conv(x), x[-1] = 0; z0 := 0 outside [0,T) (pad semantics)
  float z0[CH];
  if (t >= 0 && t < T_LEN) {
    #pragma unroll
    for (int c = 0; c < CH; ++c) z0[c] = b_causal[c];
    const float* xr = x + ((size_t)b * T_LEN + t) * CIN;
    for (int ci = 0; ci < CIN; ci += 4) {
      float4 xc = *(const float4*)(xr + ci);
      float4 xp = make_float4(0.f, 0.f, 0.f, 0.f);
      if (t > 0) xp = *(const float4*)(xr - CIN + ci);
      #pragma unroll
      for (int c = 0; c < CH; ++c) {
        const float* w = w_causal + (size_t)(c * CIN + ci) * 2;  // [c][ci][k]
        z0[c] += w[0] * xp.x + w[1] * xc.x
               + w[2] * xp.y + w[3] * xc.y
               + w[4] * xp.z + w[5] * xc.z
               + w[6] * xp.w + w[7] * xc.w;
      }
    }
  } else {
    #pragma unroll
    for (int c = 0; c < CH; ++c) z0[c] = 0.f;
  }
  #pragma unroll
  for (int c = 0; c < CH; ++c) zbuf[c][tid] = z0[c];
  __syncthreads();

  // ---- phase 2: block0 dilated conv (dil=1) + gate -> gbuf
  const int cp1 = (tid >= 1) ? tid - 1 : 0;   // tid==0 result unused (halo)
  float d0[CH];
  #pragma unroll
  for (int c = 0; c < CH; ++c) d0[c] = bd0[c];
  for (int ci = 0; ci < CH; ++ci) {           // dynamic ci: uniform -> weight s_loads
    float zpv = zbuf[ci][cp1];
    float zcv = zbuf[ci][tid];
    #pragma unroll
    for (int c = 0; c < CH; ++c)
      d0[c] += wd0[(c * CH + ci) * 2] * zpv + wd0[(c * CH + ci) * 2 + 1] * zcv;
  }
  #pragma unroll
  for (int c = 0; c < CH; ++c) gbuf[c][tid] = gated(d0[c]);
  __syncthreads();

  // ---- phase 3: skip = bs0 + ws0*g0 ; z1 = z0 + bo0 + wo0*g0 -> zbuf
  float skip[CH], z1[CH];
  #pragma unroll
  for (int c = 0; c < CH; ++c) { skip[c] = bs0[c]; z1[c] = z0[c] + bo0[c]; }
  for (int ci = 0; ci < CH; ++ci) {
    float gv = gbuf[ci][tid];
    #pragma unroll
    for (int c = 0; c < CH; ++c) {
      skip[c] += ws0[c * CH + ci] * gv;
      z1[c]   += wo0[c * CH + ci] * gv;
    }
  }
  if (t < 0) {   // z pad semantics for block-1's t-2 tap at global left edge
    #pragma unroll
    for (int c = 0; c < CH; ++c) z1[c] = 0.f;
  }
  #pragma unroll
  for (int c = 0; c < CH; ++c) zbuf[c][tid] = z1[c];
  __syncthreads();

  // ---- phase 4: block1 dilated conv (dil=2) + gate -> gbuf
  const int cp2 = (tid >= 2) ? tid - 2 : 0;   // tid<2 results unused (halo)
  float d1[CH];
  #pragma unroll
  for (int c = 0; c < CH; ++c) d1[c] = bd1[c];
  for (int ci = 0; ci < CH; ++ci) {
    float zpv = zbuf[ci][cp2];
    float zcv = zbuf[ci][tid];
    #pragma unroll
    for (int c = 0; c < CH; ++c)
      d1[c] += wd1[(c * CH + ci) * 2] * zpv + wd1[(c * CH + ci) * 2 + 1] * zcv;
  }
  #pragma unroll
  for (int c = 0; c < CH; ++c) gbuf[c][tid] = gated(d1[c]);
  __syncthreads();

  // ---- phase 5: skip += bs1 + ws1*g1 ; relu -> zbuf   (wo1/bo1 residual is dead code)
  #pragma unroll
  for (int c = 0; c < CH; ++c) skip[c] += bs1[c];
  for (int ci = 0; ci < CH; ++ci) {
    float gv = gbuf[ci][tid];
    #pragma unroll
    for (int c = 0; c < CH; ++c) skip[c] += ws1[c * CH + ci] * gv;
  }
  #pragma unroll
  for (int c = 0; c < CH; ++c) zbuf[c][tid] = fmaxf(skip[c], 0.f);
  __syncthreads();

  // ---- phase 6: h = relu(b_sk1 + w_sk1 * relu(skip)); store to workspace
  float h[CH];
  #pragma unroll
  for (int c = 0; c < CH; ++c) h[c] = b_sk1[c];
  for (int ci = 0; ci < CH; ++ci) {
    float rv = zbuf[ci][tid];
    #pragma unroll
    for (int c = 0; c < CH; ++c) h[c] += w_sk1[c * CH + ci] * rv;
  }
  if (tid >= 3 && t < T_LEN) {   // t >= t_base >= 0 guaranteed for tid>=3
    float* hr = h_out + ((size_t)b * T_LEN + t) * CH;
    #pragma unroll
    for (int c = 0; c < CH; c += 4) {
      float4 v = make_float4(fmaxf(h[c],   0.f), fmaxf(h[c+1], 0.f),
                             fmaxf(h[c+2], 0.f), fmaxf(h[c+3], 0.f));
      *(float4*)(hr + c) = v;
    }
  }
}

// Output head: out[r, co] = b_sk2[co] + sum_ci w_sk2[co,ci] * h[r,ci]
// 448 threads = 7 waves; thread co keeps its weight column in 32 VGPRs;
// h-row loads are wave-uniform (L1 broadcast / scalar); stores lane-coalesced.
__global__ __launch_bounds__(COUT) void dicnn_out(
    const float* __restrict__ h, const float* __restrict__ w_sk2,
    const float* __restrict__ b_sk2, float* __restrict__ out)
{
  const int co = threadIdx.x;
  const size_t r0 = (size_t)blockIdx.x * TR_B;
  float w[CH];
  #pragma unroll
  for (int i = 0; i < CH; i += 4) {
    float4 v = *(const float4*)(w_sk2 + (size_t)co * CH + i);
    w[i] = v.x; w[i+1] = v.y; w[i+2] = v.z; w[i+3] = v.w;
  }
  const float bias = b_sk2[co];
  for (int r = 0; r < TR_B; ++r) {
    const float* hr = h + (r0 + r) * CH;
    float a0 = bias, a1 = 0.f, a2 = 0.f, a3 = 0.f;  // 4 chains for ILP
    #pragma unroll
    for (int i = 0; i < CH; i += 4) {
      float4 hv = *(const float4*)(hr + i);
      a0 += w[i]   * hv.x;  a1 += w[i+1] * hv.y;
      a2 += w[i+2] * hv.z;  a3 += w[i+3] * hv.w;
    }
    out[(r0 + r) * COUT + co] = (a0 + a1) + (a2 + a3);
  }
}

extern "C" void kernel_launch(void* const* d_in, const int* in_sizes, int n_in,
                              void* d_out, int out_size, void* d_ws, size_t ws_size,
                              hipStream_t stream) {
  (void)in_sizes; (void)n_in; (void)out_size; (void)ws_size;
  const float* x        = (const float*)d_in[0];
  const float* w_causal = (const float*)d_in[1];
  const float* b_causal = (const float*)d_in[2];
  const float* wd0      = (const float*)d_in[3];
  const float* bd0      = (const float*)d_in[4];
  const float* ws0      = (const float*)d_in[5];
  const float* bs0      = (const float*)d_in[6];
  const float* wo0      = (const float*)d_in[7];
  const float* bo0      = (const float*)d_in[8];
  const float* wd1      = (const float*)d_in[9];
  const float* bd1      = (const float*)d_in[10];
  const float* ws1      = (const float*)d_in[11];
  const float* bs1      = (const float*)d_in[12];
  // d_in[13] (wo1), d_in[14] (bo1): dead in the reference graph (z unused after last block)
  const float* w_sk1    = (const float*)d_in[15];
  const float* b_sk1    = (const float*)d_in[16];
  const float* w_sk2    = (const float*)d_in[17];
  const float* b_sk2    = (const float*)d_in[18];
  float* out = (float*)d_out;
  float* hws = (float*)d_ws;   // needs B*T*CH*4 = 16.8 MB

  dim3 gA((T_LEN + TT_OUT - 1) / TT_OUT, NB);           // 17 x 32
  dicnn_front<<<gA, BLK_A, 0, stream>>>(x, w_causal, b_causal,
      wd0, bd0, ws0, bs0, wo0, bo0,
      wd1, bd1, ws1, bs1, w_sk1, b_sk1, hws);

  dim3 gB((NB * T_LEN) / TR_B);                         // 1024
  dicnn_out<<<gB, COUT, 0, stream>>>(hws, w_sk2, b_sk2, out);
}

// Round 3
// 476.975 us; speedup vs baseline: 1.2636x; 1.2636x over previous
//
#include <hip/hip_runtime.h>

#define T_LEN 4096
#define NB    32
#define CIN   64
#define CH    32
#define COUT  448
#define COLS  64      // columns (timesteps) per block
#define HALO  3
#define OUTC  (COLS - HALO)   // 61 output columns per block
#define BLK_A 256
#define TR_B  16      // rows per block in output head

// workspace layout (floats): [0, 4194304) h ; [4194304, +12288) transposed weights
#define H_ELEMS  (NB * T_LEN * CH)   // 4,194,304
#define WT_C   0        // [ci][k][32c]  4096
#define WT_D0  4096     // [ci][k][32c]  2048
#define WT_D1  6144
#define WT_S0  8192     // [ci][32c]     1024
#define WT_O0  9216
#define WT_S1  10240
#define WT_K1  11264
#define WT_N   12288

// gated activation: tanh(d) * sigmoid(d)
__device__ __forceinline__ float gated(float d) {
  float dc = fminf(fmaxf(d, -30.0f), 30.0f);
  float e2 = __expf(-2.0f * dc);
  float th = (1.0f - e2) / (1.0f + e2);
  float sg = 1.0f / (1.0f + __expf(-dc));
  return th * sg;
}

// Transpose all weights into s_load_dwordx8-friendly layouts: channel-contiguous.
__global__ void dicnn_prep(const float* __restrict__ wc,
    const float* __restrict__ wd0, const float* __restrict__ wd1,
    const float* __restrict__ ws0, const float* __restrict__ wo0,
    const float* __restrict__ ws1, const float* __restrict__ wk1,
    float* __restrict__ wt)
{
  int i = blockIdx.x * 256 + threadIdx.x;
  if (i >= WT_N) return;
  float v;
  if (i < WT_D0) {                         // wt_c[ci][k][c] <- wc[c][ci][k], ci<64
    int c = i & 31, k = (i >> 5) & 1, ci = i >> 6;
    v = wc[c * 128 + ci * 2 + k];
  } else if (i < WT_D1) {                  // wt_d0[ci][k][c] <- wd0[c][ci][k], ci<32
    int j = i - WT_D0; int c = j & 31, k = (j >> 5) & 1, ci = j >> 6;
    v = wd0[c * 64 + ci * 2 + k];
  } else if (i < WT_S0) {
    int j = i - WT_D1; int c = j & 31, k = (j >> 5) & 1, ci = j >> 6;
    v = wd1[c * 64 + ci * 2 + k];
  } else if (i < WT_O0) {                  // wt_s0[ci][c] <- ws0[c][ci]
    int j = i - WT_S0; int c = j & 31, ci = j >> 5;
    v = ws0[c * 32 + ci];
  } else if (i < WT_S1) {
    int j = i - WT_O0; int c = j & 31, ci = j >> 5;
    v = wo0[c * 32 + ci];
  } else if (i < WT_K1) {
    int j = i - WT_S1; int c = j & 31, ci = j >> 5;
    v = ws1[c * 32 + ci];
  } else {
    int j = i - WT_K1; int c = j & 31, ci = j >> 5;
    v = wk1[c * 32 + ci];
  }
  wt[i] = v;
}

// Fused front end. Block = 64 cols x 4 channel-groups (8 out-ch per thread).
// LDS [ch][col]: lanes are consecutive cols -> stride-1 -> conflict-free b32.
__global__ __launch_bounds__(BLK_A, 8) void dicnn_front(
    const float* __restrict__ x, const float* __restrict__ wt,
    const float* __restrict__ b_causal,
    const float* __restrict__ bd0, const float* __restrict__ bs0,
    const float* __restrict__ bo0, const float* __restrict__ bd1,
    const float* __restrict__ bs1, const float* __restrict__ b_sk1,
    float* __restrict__ h_out)
{
  __shared__ float zbuf[CH][COLS];
  __shared__ float gbuf[CH][COLS];

  const int tid = threadIdx.x;
  const int col = tid & 63;
  // channel-group base; readfirstlane so the compiler proves wave-uniformity
  // and scalarizes all weight/bias loads (s_load_dwordx8 from transposed layout).
  const int c0  = __builtin_amdgcn_readfirstlane((tid >> 6) << 3);
  const int b   = blockIdx.y;
  const int t   = blockIdx.x * OUTC - HALO + col;

  const float* wt_c  = wt + WT_C;
  const float* wt_d0 = wt + WT_D0;
  const float* wt_d1 = wt + WT_D1;
  const float* wt_s0 = wt + WT_S0;
  const float* wt_o0 = wt + WT_O0;
  const float* wt_s1 = wt + WT_S1;
  const float* wt_k1 = wt + WT_K1;

  // ---- phase 1: z0 = causal conv(x); z0 = 0 outside [0,T)
  float z0[8];
  #pragma unroll
  for (int c = 0; c < 8; ++c) z0[c] = 0.f;
  if (t >= 0 && t < T_LEN) {
    #pragma unroll
    for (int c = 0; c < 8; ++c) z0[c] = b_causal[c0 + c];
    const float* xr = x + ((size_t)b * T_LEN + t) * CIN;
    for (int ci = 0; ci < CIN; ci += 4) {
      float4 xc = *(const float4*)(xr + ci);
      float4 xp = make_float4(0.f, 0.f, 0.f, 0.f);
      if (t > 0) xp = *(const float4*)(xr - CIN + ci);
      #pragma unroll
      for (int j = 0; j < 4; ++j) {
        const float* wp = wt_c + (ci + j) * 64 + c0;   // k=0 at +0, k=1 at +32
        const float xpv = (&xp.x)[j];
        const float xcv = (&xc.x)[j];
        #pragma unroll
        for (int c = 0; c < 8; ++c)
          z0[c] += wp[c] * xpv + wp[32 + c] * xcv;
      }
    }
  }
  #pragma unroll
  for (int c = 0; c < 8; ++c) zbuf[c0 + c][col] = z0[c];
  __syncthreads();

  // ---- phase 2: block0 dilated conv (dil=1) + gate -> gbuf
  const int cp1 = (col >= 1) ? col - 1 : 0;   // halo cols' results unused
  float acc[8];
  #pragma unroll
  for (int c = 0; c < 8; ++c) acc[c] = bd0[c0 + c];
  for (int ci = 0; ci < CH; ++ci) {
    float zp = zbuf[ci][cp1];
    float zc = zbuf[ci][col];
    const float* wp = wt_d0 + ci * 64 + c0;
    #pragma unroll
    for (int c = 0; c < 8; ++c)
      acc[c] += wp[c] * zp + wp[32 + c] * zc;
  }
  #pragma unroll
  for (int c = 0; c < 8; ++c) gbuf[c0 + c][col] = gated(acc[c]);
  __syncthreads();

  // ---- phase 3: skip = bs0 + ws0*g0 ; z1 = z0 + bo0 + wo0*g0 -> zbuf
  float skip[8], z1[8];
  #pragma unroll
  for (int c = 0; c < 8; ++c) { skip[c] = bs0[c0 + c]; z1[c] = z0[c] + bo0[c0 + c]; }
  for (int ci = 0; ci < CH; ++ci) {
    float gv = gbuf[ci][col];
    const float* wsp = wt_s0 + ci * 32 + c0;
    const float* wop = wt_o0 + ci * 32 + c0;
    #pragma unroll
    for (int c = 0; c < 8; ++c) { skip[c] += wsp[c] * gv; z1[c] += wop[c] * gv; }
  }
  if (t < 0) {   // z pad semantics for block-1's t-2 tap at the global left edge
    #pragma unroll
    for (int c = 0; c < 8; ++c) z1[c] = 0.f;
  }
  #pragma unroll
  for (int c = 0; c < 8; ++c) zbuf[c0 + c][col] = z1[c];
  __syncthreads();

  // ---- phase 4: block1 dilated conv (dil=2) + gate -> gbuf
  const int cp2 = (col >= 2) ? col - 2 : 0;
  #pragma unroll
  for (int c = 0; c < 8; ++c) acc[c] = bd1[c0 + c];
  for (int ci = 0; ci < CH; ++ci) {
    float zp = zbuf[ci][cp2];
    float zc = zbuf[ci][col];
    const float* wp = wt_d1 + ci * 64 + c0;
    #pragma unroll
    for (int c = 0; c < 8; ++c)
      acc[c] += wp[c] * zp + wp[32 + c] * zc;
  }
  #pragma unroll
  for (int c = 0; c < 8; ++c) gbuf[c0 + c][col] = gated(acc[c]);
  __syncthreads();

  // ---- phase 5: skip += bs1 + ws1*g1 ; relu -> zbuf  (wo1/bo1 dead in ref graph)
  #pragma unroll
  for (int c = 0; c < 8; ++c) skip[c] += bs1[c0 + c];
  for (int ci = 0; ci < CH; ++ci) {
    float gv = gbuf[ci][col];
    const float* wsp = wt_s1 + ci * 32 + c0;
    #pragma unroll
    for (int c = 0; c < 8; ++c) skip[c] += wsp[c] * gv;
  }
  #pragma unroll
  for (int c = 0; c < 8; ++c) zbuf[c0 + c][col] = fmaxf(skip[c], 0.f);
  __syncthreads();

  // ---- phase 6: h = relu(b_sk1 + w_sk1 * relu(skip)) -> workspace
  float h[8];
  #pragma unroll
  for (int c = 0; c < 8; ++c) h[c] = b_sk1[c0 + c];
  for (int ci = 0; ci < CH; ++ci) {
    float rv = zbuf[ci][col];
    const float* wkp = wt_k1 + ci * 32 + c0;
    #pragma unroll
    for (int c = 0; c < 8; ++c) h[c] += wkp[c] * rv;
  }
  if (col >= HALO && t < T_LEN) {   // col>=3 implies t>=0
    float* hr = h_out + ((size_t)b * T_LEN + t) * CH + c0;
    float4 v0 = make_float4(fmaxf(h[0], 0.f), fmaxf(h[1], 0.f),
                            fmaxf(h[2], 0.f), fmaxf(h[3], 0.f));
    float4 v1 = make_float4(fmaxf(h[4], 0.f), fmaxf(h[5], 0.f),
                            fmaxf(h[6], 0.f), fmaxf(h[7], 0.f));
    *(float4*)(hr)     = v0;
    *(float4*)(hr + 4) = v1;
  }
}

// Output head: out[r, co] = b_sk2[co] + sum_ci w_sk2[co,ci] * h[r,ci]
// 448 threads (7 waves); h-row loads are provably uniform -> scalar loads;
// stores lane-coalesced. 16 rows/block -> 8192 blocks for pipeline depth.
__global__ __launch_bounds__(COUT) void dicnn_out(
    const float* __restrict__ h, const float* __restrict__ w_sk2,
    const float* __restrict__ b_sk2, float* __restrict__ out)
{
  const int co = threadIdx.x;
  const size_t r0 = (size_t)blockIdx.x * TR_B;
  float w[CH];
  #pragma unroll
  for (int i = 0; i < CH; i += 4) {
    float4 v = *(const float4*)(w_sk2 + (size_t)co * CH + i);
    w[i] = v.x; w[i+1] = v.y; w[i+2] = v.z; w[i+3] = v.w;
  }
  const float bias = b_sk2[co];
  #pragma unroll 2
  for (int r = 0; r < TR_B; ++r) {
    const float* hr = h + (r0 + r) * CH;
    float a0 = bias, a1 = 0.f, a2 = 0.f, a3 = 0.f;
    #pragma unroll
    for (int i = 0; i < CH; i += 4) {
      float4 hv = *(const float4*)(hr + i);
      a0 += w[i]   * hv.x;  a1 += w[i+1] * hv.y;
      a2 += w[i+2] * hv.z;  a3 += w[i+3] * hv.w;
    }
    out[(r0 + r) * COUT + co] = (a0 + a1) + (a2 + a3);
  }
}

extern "C" void kernel_launch(void* const* d_in, const int* in_sizes, int n_in,
                              void* d_out, int out_size, void* d_ws, size_t ws_size,
                              hipStream_t stream) {
  (void)in_sizes; (void)n_in; (void)out_size; (void)ws_size;
  const float* x        = (const float*)d_in[0];
  const float* w_causal = (const float*)d_in[1];
  const float* b_causal = (const float*)d_in[2];
  const float* wd0      = (const float*)d_in[3];
  const float* bd0      = (const float*)d_in[4];
  const float* ws0      = (const float*)d_in[5];
  const float* bs0      = (const float*)d_in[6];
  const float* wo0      = (const float*)d_in[7];
  const float* bo0      = (const float*)d_in[8];
  const float* wd1      = (const float*)d_in[9];
  const float* bd1      = (const float*)d_in[10];
  const float* ws1      = (const float*)d_in[11];
  const float* bs1      = (const float*)d_in[12];
  // d_in[13] (wo1), d_in[14] (bo1): dead in the reference graph
  const float* w_sk1    = (const float*)d_in[15];
  const float* b_sk1    = (const float*)d_in[16];
  const float* w_sk2    = (const float*)d_in[17];
  const float* b_sk2    = (const float*)d_in[18];
  float* out = (float*)d_out;
  float* hws = (float*)d_ws;                 // h: 16 MB
  float* wt  = (float*)d_ws + H_ELEMS;       // transposed weights: 48 KB

  dicnn_prep<<<(WT_N + 255) / 256, 256, 0, stream>>>(
      w_causal, wd0, wd1, ws0, wo0, ws1, w_sk1, wt);

  dim3 gA((T_LEN + OUTC - 1) / OUTC, NB);    // 68 x 32
  dicnn_front<<<gA, BLK_A, 0, stream>>>(x, wt, b_causal,
      bd0, bs0, bo0, bd1, bs1, b_sk1, hws);

  dim3 gB((NB * T_LEN) / TR_B);              // 8192
  dicnn_out<<<gB, COUT, 0, stream>>>(hws, w_sk2, b_sk2, out);
}

// Round 7
// 439.823 us; speedup vs baseline: 1.3703x; 1.0845x over previous
//
#include <hip/hip_runtime.h>

#define T_LEN 4096
#define NB    32
#define CIN   64
#define CH    32
#define COUT  448
#define COLS  64      // columns (timesteps) per block
#define HALO  3
#define OUTC  (COLS - HALO)   // 61 output columns per block
#define BLK_A 256
#define TR_B  16      // rows per block in output head

// workspace layout (floats): [0, 4194304) h ; [4194304, +12288) transposed weights
#define H_ELEMS  (NB * T_LEN * CH)   // 4,194,304
#define WT_C   0        // [ci][k][32c]  4096
#define WT_D0  4096     // [ci][k][32c]  2048
#define WT_D1  6144
#define WT_S0  8192     // [ci][32c]     1024
#define WT_O0  9216
#define WT_S1  10240
#define WT_K1  11264
#define WT_N   12288

// gated activation: tanh(d) * sigmoid(d)
__device__ __forceinline__ float gated(float d) {
  float dc = fminf(fmaxf(d, -30.0f), 30.0f);
  float e2 = __expf(-2.0f * dc);
  float th = (1.0f - e2) / (1.0f + e2);
  float sg = 1.0f / (1.0f + __expf(-dc));
  return th * sg;
}

// Transpose all weights into s_load_dwordx8-friendly layouts: channel-contiguous.
__global__ void dicnn_prep(const float* __restrict__ wc,
    const float* __restrict__ wd0, const float* __restrict__ wd1,
    const float* __restrict__ ws0, const float* __restrict__ wo0,
    const float* __restrict__ ws1, const float* __restrict__ wk1,
    float* __restrict__ wt)
{
  int i = blockIdx.x * 256 + threadIdx.x;
  if (i >= WT_N) return;
  float v;
  if (i < WT_D0) {                         // wt_c[ci][k][c] <- wc[c][ci][k], ci<64
    int c = i & 31, k = (i >> 5) & 1, ci = i >> 6;
    v = wc[c * 128 + ci * 2 + k];
  } else if (i < WT_D1) {                  // wt_d0[ci][k][c] <- wd0[c][ci][k], ci<32
    int j = i - WT_D0; int c = j & 31, k = (j >> 5) & 1, ci = j >> 6;
    v = wd0[c * 64 + ci * 2 + k];
  } else if (i < WT_S0) {
    int j = i - WT_D1; int c = j & 31, k = (j >> 5) & 1, ci = j >> 6;
    v = wd1[c * 64 + ci * 2 + k];
  } else if (i < WT_O0) {                  // wt_s0[ci][c] <- ws0[c][ci]
    int j = i - WT_S0; int c = j & 31, ci = j >> 5;
    v = ws0[c * 32 + ci];
  } else if (i < WT_S1) {
    int j = i - WT_O0; int c = j & 31, ci = j >> 5;
    v = wo0[c * 32 + ci];
  } else if (i < WT_K1) {
    int j = i - WT_S1; int c = j & 31, ci = j >> 5;
    v = ws1[c * 32 + ci];
  } else {
    int j = i - WT_K1; int c = j & 31, ci = j >> 5;
    v = wk1[c * 32 + ci];
  }
  wt[i] = v;
}

// Fused front end. Block = 64 cols x 4 channel-groups (8 out-ch per thread).
// LDS [ch][col]: lanes are consecutive cols -> stride-1 -> conflict-free b32.
// launch_bounds(256,4): 128-VGPR cap. (256,8) capped at 64 and spilled ~43
// floats/thread to scratch -> 97 MB excess HBM writes (round-3 counters).
__global__ __launch_bounds__(BLK_A, 4) void dicnn_front(
    const float* __restrict__ x, const float* __restrict__ wt,
    const float* __restrict__ b_causal,
    const float* __restrict__ bd0, const float* __restrict__ bs0,
    const float* __restrict__ bo0, const float* __restrict__ bd1,
    const float* __restrict__ bs1, const float* __restrict__ b_sk1,
    float* __restrict__ h_out)
{
  __shared__ float zbuf[CH][COLS];
  __shared__ float gbuf[CH][COLS];

  const int tid = threadIdx.x;
  const int col = tid & 63;
  // channel-group base; readfirstlane so the compiler proves wave-uniformity
  // and scalarizes all weight/bias loads (s_load_dwordx8 from transposed layout).
  const int c0  = __builtin_amdgcn_readfirstlane((tid >> 6) << 3);
  const int b   = blockIdx.y;
  const int t   = blockIdx.x * OUTC - HALO + col;

  const float* wt_c  = wt + WT_C;
  const float* wt_d0 = wt + WT_D0;
  const float* wt_d1 = wt + WT_D1;
  const float* wt_s0 = wt + WT_S0;
  const float* wt_o0 = wt + WT_O0;
  const float* wt_s1 = wt + WT_S1;
  const float* wt_k1 = wt + WT_K1;

  // ---- phase 1: z0 = causal conv(x); z0 = 0 outside [0,T)
  float z0[8];
  #pragma unroll
  for (int c = 0; c < 8; ++c) z0[c] = 0.f;
  if (t >= 0 && t < T_LEN) {
    #pragma unroll
    for (int c = 0; c < 8; ++c) z0[c] = b_causal[c0 + c];
    const float* xr = x + ((size_t)b * T_LEN + t) * CIN;
    for (int ci = 0; ci < CIN; ci += 4) {
      float4 xc = *(const float4*)(xr + ci);
      float4 xp = make_float4(0.f, 0.f, 0.f, 0.f);
      if (t > 0) xp = *(const float4*)(xr - CIN + ci);
      #pragma unroll
      for (int j = 0; j < 4; ++j) {
        const float* wp = wt_c + (ci + j) * 64 + c0;   // k=0 at +0, k=1 at +32
        const float xpv = (&xp.x)[j];
        const float xcv = (&xc.x)[j];
        #pragma unroll
        for (int c = 0; c < 8; ++c)
          z0[c] += wp[c] * xpv + wp[32 + c] * xcv;
      }
    }
  }
  #pragma unroll
  for (int c = 0; c < 8; ++c) zbuf[c0 + c][col] = z0[c];
  __syncthreads();

  // ---- phase 2: block0 dilated conv (dil=1) + gate -> gbuf
  const int cp1 = (col >= 1) ? col - 1 : 0;   // halo cols' results unused
  float acc[8];
  #pragma unroll
  for (int c = 0; c < 8; ++c) acc[c] = bd0[c0 + c];
  for (int ci = 0; ci < CH; ++ci) {
    float zp = zbuf[ci][cp1];
    float zc = zbuf[ci][col];
    const float* wp = wt_d0 + ci * 64 + c0;
    #pragma unroll
    for (int c = 0; c < 8; ++c)
      acc[c] += wp[c] * zp + wp[32 + c] * zc;
  }
  #pragma unroll
  for (int c = 0; c < 8; ++c) gbuf[c0 + c][col] = gated(acc[c]);
  __syncthreads();

  // ---- phase 3: skip = bs0 + ws0*g0 ; z1 = z0 + bo0 + wo0*g0 -> zbuf
  float skip[8], z1[8];
  #pragma unroll
  for (int c = 0; c < 8; ++c) { skip[c] = bs0[c0 + c]; z1[c] = z0[c] + bo0[c0 + c]; }
  for (int ci = 0; ci < CH; ++ci) {
    float gv = gbuf[ci][col];
    const float* wsp = wt_s0 + ci * 32 + c0;
    const float* wop = wt_o0 + ci * 32 + c0;
    #pragma unroll
    for (int c = 0; c < 8; ++c) { skip[c] += wsp[c] * gv; z1[c] += wop[c] * gv; }
  }
  if (t < 0) {   // z pad semantics for block-1's t-2 tap at the global left edge
    #pragma unroll
    for (int c = 0; c < 8; ++c) z1[c] = 0.f;
  }
  #pragma unroll
  for (int c = 0; c < 8; ++c) zbuf[c0 + c][col] = z1[c];
  __syncthreads();

  // ---- phase 4: block1 dilated conv (dil=2) + gate -> gbuf
  const int cp2 = (col >= 2) ? col - 2 : 0;
  #pragma unroll
  for (int c = 0; c < 8; ++c) acc[c] = bd1[c0 + c];
  for (int ci = 0; ci < CH; ++ci) {
    float zp = zbuf[ci][cp2];
    float zc = zbuf[ci][col];
    const float* wp = wt_d1 + ci * 64 + c0;
    #pragma unroll
    for (int c = 0; c < 8; ++c)
      acc[c] += wp[c] * zp + wp[32 + c] * zc;
  }
  #pragma unroll
  for (int c = 0; c < 8; ++c) gbuf[c0 + c][col] = gated(acc[c]);
  __syncthreads();

  // ---- phase 5: skip += bs1 + ws1*g1 ; relu -> zbuf  (wo1/bo1 dead in ref graph)
  #pragma unroll
  for (int c = 0; c < 8; ++c) skip[c] += bs1[c0 + c];
  for (int ci = 0; ci < CH; ++ci) {
    float gv = gbuf[ci][col];
    const float* wsp = wt_s1 + ci * 32 + c0;
    #pragma unroll
    for (int c = 0; c < 8; ++c) skip[c] += wsp[c] * gv;
  }
  #pragma unroll
  for (int c = 0; c < 8; ++c) zbuf[c0 + c][col] = fmaxf(skip[c], 0.f);
  __syncthreads();

  // ---- phase 6: h = relu(b_sk1 + w_sk1 * relu(skip)) -> workspace
  float h[8];
  #pragma unroll
  for (int c = 0; c < 8; ++c) h[c] = b_sk1[c0 + c];
  for (int ci = 0; ci < CH; ++ci) {
    float rv = zbuf[ci][col];
    const float* wkp = wt_k1 + ci * 32 + c0;
    #pragma unroll
    for (int c = 0; c < 8; ++c) h[c] += wkp[c] * rv;
  }
  if (col >= HALO && t < T_LEN) {   // col>=3 implies t>=0
    float* hr = h_out + ((size_t)b * T_LEN + t) * CH + c0;
    float4 v0 = make_float4(fmaxf(h[0], 0.f), fmaxf(h[1], 0.f),
                            fmaxf(h[2], 0.f), fmaxf(h[3], 0.f));
    float4 v1 = make_float4(fmaxf(h[4], 0.f), fmaxf(h[5], 0.f),
                            fmaxf(h[6], 0.f), fmaxf(h[7], 0.f));
    *(float4*)(hr)     = v0;
    *(float4*)(hr + 4) = v1;
  }
}

// Output head: out[r, co] = b_sk2[co] + sum_ci w_sk2[co,ci] * h[r,ci]
// 448 threads (7 waves); h-row loads are provably uniform -> scalar loads;
// stores lane-coalesced. 16 rows/block -> 8192 blocks for pipeline depth.
__global__ __launch_bounds__(COUT) void dicnn_out(
    const float* __restrict__ h, const float* __restrict__ w_sk2,
    const float* __restrict__ b_sk2, float* __restrict__ out)
{
  const int co = threadIdx.x;
  const size_t r0 = (size_t)blockIdx.x * TR_B;
  float w[CH];
  #pragma unroll
  for (int i = 0; i < CH; i += 4) {
    float4 v = *(const float4*)(w_sk2 + (size_t)co * CH + i);
    w[i] = v.x; w[i+1] = v.y; w[i+2] = v.z; w[i+3] = v.w;
  }
  const float bias = b_sk2[co];
  #pragma unroll 2
  for (int r = 0; r < TR_B; ++r) {
    const float* hr = h + (r0 + r) * CH;
    float a0 = bias, a1 = 0.f, a2 = 0.f, a3 = 0.f;
    #pragma unroll
    for (int i = 0; i < CH; i += 4) {
      float4 hv = *(const float4*)(hr + i);
      a0 += w[i]   * hv.x;  a1 += w[i+1] * hv.y;
      a2 += w[i+2] * hv.z;  a3 += w[i+3] * hv.w;
    }
    out[(r0 + r) * COUT + co] = (a0 + a1) + (a2 + a3);
  }
}

extern "C" void kernel_launch(void* const* d_in, const int* in_sizes, int n_in,
                              void* d_out, int out_size, void* d_ws, size_t ws_size,
                              hipStream_t stream) {
  (void)in_sizes; (void)n_in; (void)out_size; (void)ws_size;
  const float* x        = (const float*)d_in[0];
  const float* w_causal = (const float*)d_in[1];
  const float* b_causal = (const float*)d_in[2];
  const float* wd0      = (const float*)d_in[3];
  const float* bd0      = (const float*)d_in[4];
  const float* ws0      = (const float*)d_in[5];
  const float* bs0      = (const float*)d_in[6];
  const float* wo0      = (const float*)d_in[7];
  const float* bo0      = (const float*)d_in[8];
  const float* wd1      = (const float*)d_in[9];
  const float* bd1      = (const float*)d_in[10];
  const float* ws1      = (const float*)d_in[11];
  const float* bs1      = (const float*)d_in[12];
  // d_in[13] (wo1), d_in[14] (bo1): dead in the reference graph
  const float* w_sk1    = (const float*)d_in[15];
  const float* b_sk1    = (const float*)d_in[16];
  const float* w_sk2    = (const float*)d_in[17];
  const float* b_sk2    = (const float*)d_in[18];
  float* out = (float*)d_out;
  float* hws = (float*)d_ws;                 // h: 16 MB
  float* wt  = (float*)d_ws + H_ELEMS;       // transposed weights: 48 KB

  dicnn_prep<<<(WT_N + 255) / 256, 256, 0, stream>>>(
      w_causal, wd0, wd1, ws0, wo0, ws1, w_sk1, wt);

  dim3 gA((T_LEN + OUTC - 1) / OUTC, NB);    // 68 x 32
  dicnn_front<<<gA, BLK_A, 0, stream>>>(x, wt, b_causal,
      bd0, bs0, bo0, bd1, bs1, b_sk1, hws);

  dim3 gB((NB * T_LEN) / TR_B);              // 8192
  dicnn_out<<<gB, COUT, 0, stream>>>(hws, w_sk2, b_sk2, out);
}